// Round 1
// baseline (267.088 us; speedup 1.0000x reference)
//
#include <hip/hip_runtime.h>
#include <cstdint>
#include <cstddef>

typedef unsigned short u16;
typedef __bf16 bf16_t;
typedef bf16_t bf16x8 __attribute__((ext_vector_type(8)));
typedef float f32x4 __attribute__((ext_vector_type(4)));

#define NN 8192
#define FD 512

static_assert(sizeof(bf16x8) == 16, "bf16x8 must be 16B");

__device__ __forceinline__ u16 f2bf(float x) {
  unsigned u = __float_as_uint(x);
  u += 0x7FFFu + ((u >> 16) & 1u);   // round-to-nearest-even
  return (u16)(u >> 16);
}
__device__ __forceinline__ float bf2f(u16 v) {
  return __uint_as_float((unsigned)v << 16);
}
__device__ __forceinline__ void load_lds16(const void* g, void* l) {
  __builtin_amdgcn_global_load_lds((__attribute__((address_space(1))) void*)(g),
                                   (__attribute__((address_space(3))) void*)(l),
                                   16, 0, 0);
}

// ---------------------------------------------------------------------------
// K1: one pass over adj. rowsum[i] = sum_j adj[i][j]; colsum[j] = sum_i adj[i][j];
//     Abf = bf16(adj). grid (8 colgroups x 64 rowgroups), 256 threads.
// ---------------------------------------------------------------------------
__global__ __launch_bounds__(256) void k1_adj_pass(
    const float* __restrict__ adj, u16* __restrict__ Abf,
    float* __restrict__ rowsum, float* __restrict__ colsum) {
  const int c0 = blockIdx.x * 1024 + threadIdx.x * 4;
  const int r0 = blockIdx.y * 128;
  const int lane = threadIdx.x & 63;
  float cs0 = 0.f, cs1 = 0.f, cs2 = 0.f, cs3 = 0.f;
  for (int r = 0; r < 128; ++r) {
    const float4 v = *(const float4*)(adj + (size_t)(r0 + r) * NN + c0);
    ushort4 b;
    b.x = f2bf(v.x); b.y = f2bf(v.y); b.z = f2bf(v.z); b.w = f2bf(v.w);
    *(ushort4*)(Abf + (size_t)(r0 + r) * NN + c0) = b;
    cs0 += v.x; cs1 += v.y; cs2 += v.z; cs3 += v.w;
    float rs = v.x + v.y + v.z + v.w;
#pragma unroll
    for (int off = 32; off; off >>= 1) rs += __shfl_xor(rs, off);
    if (lane == 0) atomicAdd(&rowsum[r0 + r], rs);
  }
  atomicAdd(&colsum[c0 + 0], cs0);
  atomicAdd(&colsum[c0 + 1], cs1);
  atomicAdd(&colsum[c0 + 2], cs2);
  atomicAdd(&colsum[c0 + 3], cs3);
}

// ---------------------------------------------------------------------------
// K2: per row i: d = 0.5*(rowsum+colsum); rinv = rsqrt(d+eps);
//     Y[i][:] = bf16(rinv * X[i][:]); t1part[i] = d*rinv^2*||X_i||^2.
//     grid 8192 x 128 threads.
// ---------------------------------------------------------------------------
__global__ __launch_bounds__(128) void k2_scale(
    const float* __restrict__ X, const float* __restrict__ rowsum,
    const float* __restrict__ colsum, u16* __restrict__ Y,
    float* __restrict__ t1part) {
  const int i = blockIdx.x;
  const int t = threadIdx.x;
  const float d = 0.5f * (rowsum[i] + colsum[i]);
  const float rinv = rsqrtf(d + 1e-5f);
  const float4 x = *(const float4*)(X + (size_t)i * FD + t * 4);
  ushort4 y;
  y.x = f2bf(x.x * rinv); y.y = f2bf(x.y * rinv);
  y.z = f2bf(x.z * rinv); y.w = f2bf(x.w * rinv);
  *(ushort4*)(Y + (size_t)i * FD + t * 4) = y;
  float nsq = x.x * x.x + x.y * x.y + x.z * x.z + x.w * x.w;
#pragma unroll
  for (int off = 32; off; off >>= 1) nsq += __shfl_xor(nsq, off);
  __shared__ float red[2];
  if ((t & 63) == 0) red[t >> 6] = nsq;
  __syncthreads();
  if (t == 0) t1part[i] = (d * rinv * rinv) * (red[0] + red[1]);
}

// ---------------------------------------------------------------------------
// K2b: transpose Y [8192][512] -> Yt [512][8192] (bf16), 64x64 LDS tiles.
// ---------------------------------------------------------------------------
__global__ __launch_bounds__(256) void k2b_transpose(
    const u16* __restrict__ Y, u16* __restrict__ Yt) {
  __shared__ u16 tile[64][72];
  const int i0 = blockIdx.x * 64;
  const int f0 = blockIdx.y * 64;
  const int t = threadIdx.x;
#pragma unroll
  for (int it = 0; it < 2; ++it) {
    int u = it * 256 + t;               // 0..511 (8-elem units)
    int r = u >> 3, c8 = (u & 7) * 8;
    uint4 v = *(const uint4*)(Y + (size_t)(i0 + r) * FD + f0 + c8);
    *(uint4*)&tile[r][c8] = v;
  }
  __syncthreads();
#pragma unroll
  for (int it = 0; it < 2; ++it) {
    int u = it * 256 + t;
    int fr = u >> 3, c8 = (u & 7) * 8;
    union { u16 h[8]; uint4 v; } tmp;
#pragma unroll
    for (int j = 0; j < 8; ++j) tmp.h[j] = tile[c8 + j][fr];
    *(uint4*)(Yt + (size_t)(f0 + fr) * NN + i0 + c8) = tmp.v;
  }
}

// ---------------------------------------------------------------------------
// K3: Z[kz] = Abf[:, kz-half] @ Y[kz-half, :]  (bf16 MFMA 16x16x32)
//   BM=128, BN=128, BK=32, 4 waves (2x2), wave tile 64x64 (4x4 frags),
//   double-buffered LDS + global_load_lds(16B). K-split 2 -> grid (64,4,2).
// ---------------------------------------------------------------------------
#define BM 128
#define BN 128
#define BK 32

__global__ __launch_bounds__(256, 3) void k3_gemm(
    const u16* __restrict__ Abf, const u16* __restrict__ Yt,
    float* __restrict__ Z) {
  __shared__ u16 As[2][BM * BK];
  __shared__ u16 Bs[2][BN * BK];
  const int i0 = blockIdx.x * BM;
  const int f0 = blockIdx.y * BN;
  const int kz = blockIdx.z;
  const int t = threadIdx.x;
  const int lane = t & 63, wid = t >> 6;
  const int wm = wid >> 1, wn = wid & 1;
  const int row16 = lane & 15, kgrp = lane >> 4;  // 0..3

  f32x4 acc[4][4] = {};
  const size_t kbase0 = (size_t)kz * 4096;

  auto stage = [&](int kt, int buf) {
    const size_t kb = kbase0 + (size_t)kt * BK;
#pragma unroll
    for (int q = 0; q < 2; ++q) {
      const int unit = (wid * 2 + q) * 64 + lane;      // 0..511
      const int r = unit >> 2, c = (unit & 3) * 8;     // [128][32]
      load_lds16(Abf + (size_t)(i0 + r) * NN + kb + c,
                 &As[buf][(wid * 2 + q) * 512]);
    }
#pragma unroll
    for (int q = 0; q < 2; ++q) {
      const int unit = (wid * 2 + q) * 64 + lane;
      const int r = unit >> 2, c = (unit & 3) * 8;
      load_lds16(Yt + (size_t)(f0 + r) * NN + kb + c,
                 &Bs[buf][(wid * 2 + q) * 512]);
    }
  };

  auto compute = [&](int buf) {
    bf16x8 a[4], b[4];
    const u16* as = As[buf];
    const u16* bs = Bs[buf];
    const int kof = kgrp * 8;
#pragma unroll
    for (int m = 0; m < 4; ++m)
      a[m] = *(const bf16x8*)(as + (wm * 64 + m * 16 + row16) * BK + kof);
#pragma unroll
    for (int n = 0; n < 4; ++n)
      b[n] = *(const bf16x8*)(bs + (wn * 64 + n * 16 + row16) * BK + kof);
#pragma unroll
    for (int m = 0; m < 4; ++m)
#pragma unroll
      for (int n = 0; n < 4; ++n)
        acc[m][n] = __builtin_amdgcn_mfma_f32_16x16x32_bf16(a[m], b[n], acc[m][n], 0, 0, 0);
  };

  stage(0, 0);
  __syncthreads();
  int cur = 0;
  const int NT = 4096 / BK;  // 128
  for (int kt = 0; kt < NT - 1; ++kt) {
    stage(kt + 1, cur ^ 1);
    compute(cur);
    __syncthreads();   // drains vmcnt+lgkmcnt, flips buffers safely
    cur ^= 1;
  }
  compute(cur);

  float* Zk = Z + (size_t)kz * ((size_t)NN * FD);
#pragma unroll
  for (int m = 0; m < 4; ++m) {
    const int gr = i0 + wm * 64 + m * 16 + kgrp * 4;
#pragma unroll
    for (int n = 0; n < 4; ++n) {
      const int gc = f0 + wn * 64 + n * 16 + row16;
#pragma unroll
      for (int g = 0; g < 4; ++g)
        Zk[(size_t)(gr + g) * FD + gc] = acc[m][n][g];
    }
  }
}

// ---------------------------------------------------------------------------
// K4: out = sum(t1part) - sum((Z0+Z1) * Y)
// ---------------------------------------------------------------------------
__global__ __launch_bounds__(256) void k4_reduce(
    const float* __restrict__ Z, const u16* __restrict__ Y,
    const float* __restrict__ t1part, float* __restrict__ out) {
  const int tid = blockIdx.x * 256 + threadIdx.x;
  const int stride = gridDim.x * 256;
  float s = 0.f;
  const float4* Z0 = (const float4*)Z;
  const float4* Z1 = (const float4*)(Z + (size_t)NN * FD);
  const ushort4* Yv = (const ushort4*)Y;
  const int NU = NN * FD / 4;
  for (int u = tid; u < NU; u += stride) {
    float4 a = Z0[u], b = Z1[u];
    ushort4 y = Yv[u];
    s -= (a.x + b.x) * bf2f(y.x) + (a.y + b.y) * bf2f(y.y) +
         (a.z + b.z) * bf2f(y.z) + (a.w + b.w) * bf2f(y.w);
  }
  for (int u = tid; u < NN; u += stride) s += t1part[u];
#pragma unroll
  for (int off = 32; off; off >>= 1) s += __shfl_xor(s, off);
  __shared__ float red[4];
  if ((threadIdx.x & 63) == 0) red[threadIdx.x >> 6] = s;
  __syncthreads();
  if (threadIdx.x == 0) atomicAdd(out, red[0] + red[1] + red[2] + red[3]);
}

// ---------------------------------------------------------------------------
extern "C" void kernel_launch(void* const* d_in, const int* in_sizes, int n_in,
                              void* d_out, int out_size, void* d_ws, size_t ws_size,
                              hipStream_t stream) {
  const float* adj = (const float*)d_in[0];
  const float* X   = (const float*)d_in[1];
  float* out = (float*)d_out;
  char* ws = (char*)d_ws;

  // ws layout (bytes):
  u16*   Abf    = (u16*)(ws);                    // 134217728  (8192*8192 bf16)
  u16*   Yt     = (u16*)(ws + 134217728);        // 8388608    (512*8192 bf16)
  u16*   Y      = (u16*)(ws + 142606336);        // 8388608    (8192*512 bf16)
  float* Z      = (float*)(ws + 150994944);      // 33554432   (2 x 8192*512 f32)
  float* rowsum = (float*)(ws + 184549376);      // 32768
  float* colsum = (float*)(ws + 184582144);      // 32768
  float* t1     = (float*)(ws + 184614912);      // 32768  -> end 184647680

  hipMemsetAsync(rowsum, 0, 2 * NN * sizeof(float), stream);  // rowsum+colsum
  hipMemsetAsync(out, 0, sizeof(float), stream);

  k1_adj_pass<<<dim3(8, 64), 256, 0, stream>>>(adj, Abf, rowsum, colsum);
  k2_scale<<<NN, 128, 0, stream>>>(X, rowsum, colsum, Y, t1);
  k2b_transpose<<<dim3(128, 8), 256, 0, stream>>>(Y, Yt);
  k3_gemm<<<dim3(64, 4, 2), 256, 0, stream>>>(Abf, Yt, Z);
  k4_reduce<<<512, 256, 0, stream>>>(Z, Y, t1, out);
}

// Round 2
// 220.150 us; speedup vs baseline: 1.2132x; 1.2132x over previous
//
#include <hip/hip_runtime.h>
#include <cstdint>
#include <cstddef>

typedef unsigned short u16;
typedef __bf16 bf16_t;
typedef bf16_t bf16x4 __attribute__((ext_vector_type(4)));
typedef bf16_t bf16x8 __attribute__((ext_vector_type(8)));
typedef float f32x4 __attribute__((ext_vector_type(4)));

#define NN 8192
#define FD 512

static_assert(sizeof(bf16x8) == 16, "bf16x8 must be 16B");

__device__ __forceinline__ float bf2f(u16 v) {
  return __uint_as_float((unsigned)v << 16);
}
__device__ __forceinline__ void load_lds16(const void* g, void* l) {
  __builtin_amdgcn_global_load_lds((__attribute__((address_space(1))) void*)(g),
                                   (__attribute__((address_space(3))) void*)(l),
                                   16, 0, 0);
}

// ---------------------------------------------------------------------------
// K0: zero rowsum, colsum, out.
// ---------------------------------------------------------------------------
__global__ __launch_bounds__(256) void k0_init(float* __restrict__ rowsum,
                                               float* __restrict__ colsum,
                                               float* __restrict__ out) {
  const int i = blockIdx.x * 256 + threadIdx.x;
  if (i < NN) { rowsum[i] = 0.f; colsum[i] = 0.f; }
  if (i == 0) out[0] = 0.f;
}

// ---------------------------------------------------------------------------
// K1a: convert adj -> Abf (bf16) and rowsum (register accumulation).
//   Block tile: 16 rows x 8192 cols. 256 thr = 16 row-slots x 16 col-slots.
//   grid 512. HBM-bound: ~9 VALU per 24B traffic.
// ---------------------------------------------------------------------------
__global__ __launch_bounds__(256) void k1a_convert_rowsum(
    const float* __restrict__ adj, u16* __restrict__ Abf,
    float* __restrict__ rowsum) {
  const int rs = threadIdx.x >> 4;   // 0..15
  const int cs = threadIdx.x & 15;   // 0..15
  const int row = blockIdx.x * 16 + rs;
  const float* src = adj + (size_t)row * NN;
  u16* dst = Abf + (size_t)row * NN;
  float acc = 0.f;
#pragma unroll 4
  for (int m = 0; m < 128; ++m) {
    const int c = (m * 16 + cs) * 4;
    const float4 v = *(const float4*)(src + c);
    bf16x4 b;
    b.x = (bf16_t)v.x; b.y = (bf16_t)v.y; b.z = (bf16_t)v.z; b.w = (bf16_t)v.w;
    *(bf16x4*)(dst + c) = b;
    acc += (v.x + v.y) + (v.z + v.w);
  }
  acc += __shfl_xor(acc, 1);
  acc += __shfl_xor(acc, 2);
  acc += __shfl_xor(acc, 4);
  acc += __shfl_xor(acc, 8);
  if (cs == 0) rowsum[row] = acc;
}

// ---------------------------------------------------------------------------
// K1b: colsum from Abf (bf16, 128MB read). Each thread owns 4 columns,
//   register accumulators, 4 atomics at end. grid 1024 (8 colgrp x 128 rowgrp).
// ---------------------------------------------------------------------------
__global__ __launch_bounds__(256) void k1b_colsum(
    const u16* __restrict__ Abf, float* __restrict__ colsum) {
  const int c0 = (blockIdx.x & 7) * 1024 + threadIdx.x * 4;
  const int r0 = (blockIdx.x >> 3) * 64;
  float a0 = 0.f, a1 = 0.f, a2 = 0.f, a3 = 0.f;
#pragma unroll 4
  for (int r = 0; r < 64; ++r) {
    const ushort4 v = *(const ushort4*)(Abf + (size_t)(r0 + r) * NN + c0);
    a0 += bf2f(v.x); a1 += bf2f(v.y); a2 += bf2f(v.z); a3 += bf2f(v.w);
  }
  atomicAdd(&colsum[c0 + 0], a0);
  atomicAdd(&colsum[c0 + 1], a1);
  atomicAdd(&colsum[c0 + 2], a2);
  atomicAdd(&colsum[c0 + 3], a3);
}

// ---------------------------------------------------------------------------
// K2: per row i: d = 0.5*(rowsum+colsum); rinv = rsqrt(d+eps);
//     Y[i][:] = bf16(rinv*X[i][:]); t1part[i] = d*rinv^2*||X_i||^2.
// ---------------------------------------------------------------------------
__global__ __launch_bounds__(128) void k2_scale(
    const float* __restrict__ X, const float* __restrict__ rowsum,
    const float* __restrict__ colsum, u16* __restrict__ Y,
    float* __restrict__ t1part) {
  const int i = blockIdx.x;
  const int t = threadIdx.x;
  const float d = 0.5f * (rowsum[i] + colsum[i]);
  const float rinv = rsqrtf(d + 1e-5f);
  const float4 x = *(const float4*)(X + (size_t)i * FD + t * 4);
  bf16x4 y;
  y.x = (bf16_t)(x.x * rinv); y.y = (bf16_t)(x.y * rinv);
  y.z = (bf16_t)(x.z * rinv); y.w = (bf16_t)(x.w * rinv);
  *(bf16x4*)(Y + (size_t)i * FD + t * 4) = y;
  float nsq = x.x * x.x + x.y * x.y + x.z * x.z + x.w * x.w;
#pragma unroll
  for (int off = 32; off; off >>= 1) nsq += __shfl_xor(nsq, off);
  __shared__ float red[2];
  if ((t & 63) == 0) red[t >> 6] = nsq;
  __syncthreads();
  if (t == 0) t1part[i] = (d * rinv * rinv) * (red[0] + red[1]);
}

// ---------------------------------------------------------------------------
// K2b: transpose Y [8192][512] -> Yt [512][8192] (bf16), 64x64 LDS tiles.
// ---------------------------------------------------------------------------
__global__ __launch_bounds__(256) void k2b_transpose(
    const u16* __restrict__ Y, u16* __restrict__ Yt) {
  __shared__ u16 tile[64][72];
  const int i0 = blockIdx.x * 64;
  const int f0 = blockIdx.y * 64;
  const int t = threadIdx.x;
#pragma unroll
  for (int it = 0; it < 2; ++it) {
    int u = it * 256 + t;
    int r = u >> 3, c8 = (u & 7) * 8;
    uint4 v = *(const uint4*)(Y + (size_t)(i0 + r) * FD + f0 + c8);
    *(uint4*)&tile[r][c8] = v;
  }
  __syncthreads();
#pragma unroll
  for (int it = 0; it < 2; ++it) {
    int u = it * 256 + t;
    int fr = u >> 3, c8 = (u & 7) * 8;
    union { u16 h[8]; uint4 v; } tmp;
#pragma unroll
    for (int j = 0; j < 8; ++j) tmp.h[j] = tile[c8 + j][fr];
    *(uint4*)(Yt + (size_t)(f0 + fr) * NN + i0 + c8) = tmp.v;
  }
}

// ---------------------------------------------------------------------------
// K3: Z[ks] = Abf[:, ks-quarter] @ Y[ks-quarter, :]
//   BM=BN=256, BK=32, 8 waves (2Mx4N), wave tile 128x64 (8x4 frags 16x16x32).
//   4-deep circular LDS pipeline (4 bufs x (A 16KB + B 16KB) = 128 KiB):
//   per K-tile: vmcnt(8) -> s_barrier -> issue stage(T+3) -> 12 ds_read_b128
//   -> 32 MFMA (setprio-wrapped). Loads for T+1,T+2 stay in flight across
//   the barrier (counted vmcnt, never 0 in steady state).
//   LDS swizzle (involution, both-sides): a ^= (a>>3)&0x70 -> 8 lanes per
//   16B slot on frag ds_read_b128 = b128 floor (conflict-free).
// ---------------------------------------------------------------------------
#define BKk 32
#define KSPLIT 4
#define KPB (NN / KSPLIT)    // 2048
#define NTILES (KPB / BKk)   // 64

__global__ __launch_bounds__(512, 2) void k3_gemm(
    const u16* __restrict__ Abf, const u16* __restrict__ Yt,
    float* __restrict__ Z) {
  __shared__ u16 smem[4 * 16384];  // 128 KiB: buf*16384 | A[0..8191] B[8192..16383]
  const int t = threadIdx.x;
  const int lane = t & 63, wid = t >> 6;
  const int wm = wid >> 2, wn = wid & 3;
  const int row16 = lane & 15, kgrp = lane >> 4;

  // XCD-bijective block swizzle: pair the two N-tiles of one (mt,ks) A-panel
  // on the same XCD.
  const int bid = blockIdx.x;
  const int xcd = bid & 7, j = bid >> 3;       // j 0..31
  const int nt = j & 1;
  const int p = xcd * 16 + (j >> 1);           // 0..127
  const int mt = p & 31, ks = p >> 5;
  const int i0 = mt * 256;
  const int f0 = nt * 256;
  const size_t kb0 = (size_t)ks * KPB;

  f32x4 acc[8][4] = {};

  // swizzled per-lane frag base (u16 units within one operand tile)
  const int pbu = ((row16 * 64 + kgrp * 16) ^ ((row16 & 0xE) << 3)) >> 1;
  const int abase = wm * 4096 + pbu;           // + m*512
  const int bbase = 8192 + wn * 2048 + pbu;    // + n*512

  // staging: dest linear, source pre-swizzled (same involution)
  const int soff_xor = (t & 0x38) << 1;        // ((off>>3)&0x70) for off=(q*512+t)*16

  auto stage = [&](int T) {
    const int buf = T & 3;
    const size_t kb = kb0 + (size_t)T * BKk;
#pragma unroll
    for (int q = 0; q < 2; ++q) {
      const int off = (q * 512 + t) * 16;
      const int soff = off ^ soff_xor;
      const int arow = soff >> 6;              // 0..255
      const int ain = (soff & 63) >> 1;        // u16 in row
      load_lds16(Abf + (size_t)(i0 + arow) * NN + kb + ain,
                 &smem[buf * 16384 + q * 4096 + wid * 512]);
    }
#pragma unroll
    for (int q = 0; q < 2; ++q) {
      const int off = (q * 512 + t) * 16;
      const int soff = off ^ soff_xor;
      const int brow = soff >> 6;
      const int bin = (soff & 63) >> 1;
      load_lds16(Yt + (size_t)(f0 + brow) * NN + kb + bin,
                 &smem[buf * 16384 + 8192 + q * 4096 + wid * 512]);
    }
  };

  auto compute = [&](int T) {
    const u16* s = &smem[(T & 3) * 16384];
    bf16x8 a[8], b[4];
#pragma unroll
    for (int m = 0; m < 8; ++m) a[m] = *(const bf16x8*)(s + abase + m * 512);
#pragma unroll
    for (int n = 0; n < 4; ++n) b[n] = *(const bf16x8*)(s + bbase + n * 512);
    __builtin_amdgcn_s_setprio(1);
#pragma unroll
    for (int m = 0; m < 8; ++m)
#pragma unroll
      for (int n = 0; n < 4; ++n)
        acc[m][n] = __builtin_amdgcn_mfma_f32_16x16x32_bf16(a[m], b[n], acc[m][n], 0, 0, 0);
    __builtin_amdgcn_s_setprio(0);
  };

  stage(0);
  stage(1);
  stage(2);
  for (int T = 0; T < NTILES; ++T) {
    if (T < NTILES - 2)
      asm volatile("s_waitcnt vmcnt(8)" ::: "memory");   // tile T landed; T+1,T+2 in flight
    else if (T == NTILES - 2)
      asm volatile("s_waitcnt vmcnt(4)" ::: "memory");
    else
      asm volatile("s_waitcnt vmcnt(0)" ::: "memory");
    __builtin_amdgcn_s_barrier();
    if (T + 3 < NTILES) stage(T + 3);   // targets buf (T-1)&3: reads drained before barrier
    compute(T);
  }

  float* Zk = Z + (size_t)ks * ((size_t)NN * FD);
#pragma unroll
  for (int m = 0; m < 8; ++m) {
    const int gr = i0 + wm * 128 + m * 16 + kgrp * 4;
#pragma unroll
    for (int n = 0; n < 4; ++n) {
      const int gc = f0 + wn * 64 + n * 16 + row16;
#pragma unroll
      for (int g = 0; g < 4; ++g)
        Zk[(size_t)(gr + g) * FD + gc] = acc[m][n][g];
    }
  }
}

// ---------------------------------------------------------------------------
// K4: out = sum(t1part) - sum((Z0+Z1+Z2+Z3) * Y)
// ---------------------------------------------------------------------------
__global__ __launch_bounds__(256) void k4_reduce(
    const float* __restrict__ Z, const u16* __restrict__ Y,
    const float* __restrict__ t1part, float* __restrict__ out) {
  const int tid = blockIdx.x * 256 + threadIdx.x;
  const int stride = gridDim.x * 256;
  float s = 0.f;
  const float4* Z0 = (const float4*)Z;
  const float4* Z1 = (const float4*)(Z + 1 * (size_t)NN * FD);
  const float4* Z2 = (const float4*)(Z + 2 * (size_t)NN * FD);
  const float4* Z3 = (const float4*)(Z + 3 * (size_t)NN * FD);
  const ushort4* Yv = (const ushort4*)Y;
  const int NU = NN * FD / 4;
  for (int u = tid; u < NU; u += stride) {
    const float4 a = Z0[u], b = Z1[u], c = Z2[u], d = Z3[u];
    const ushort4 y = Yv[u];
    s -= (a.x + b.x + c.x + d.x) * bf2f(y.x) + (a.y + b.y + c.y + d.y) * bf2f(y.y) +
         (a.z + b.z + c.z + d.z) * bf2f(y.z) + (a.w + b.w + c.w + d.w) * bf2f(y.w);
  }
  for (int u = tid; u < NN; u += stride) s += t1part[u];
#pragma unroll
  for (int off = 32; off; off >>= 1) s += __shfl_xor(s, off);
  __shared__ float red[4];
  if ((threadIdx.x & 63) == 0) red[threadIdx.x >> 6] = s;
  __syncthreads();
  if (threadIdx.x == 0) atomicAdd(out, red[0] + red[1] + red[2] + red[3]);
}

// ---------------------------------------------------------------------------
extern "C" void kernel_launch(void* const* d_in, const int* in_sizes, int n_in,
                              void* d_out, int out_size, void* d_ws, size_t ws_size,
                              hipStream_t stream) {
  const float* adj = (const float*)d_in[0];
  const float* X   = (const float*)d_in[1];
  float* out = (float*)d_out;
  char* ws = (char*)d_ws;

  // ws layout (bytes):
  u16*   Abf    = (u16*)(ws);                    // 134217728  (8192*8192 bf16)
  u16*   Yt     = (u16*)(ws + 134217728);        // 8388608    (512*8192 bf16)
  u16*   Y      = (u16*)(ws + 142606336);        // 8388608    (8192*512 bf16)
  float* Z      = (float*)(ws + 150994944);      // 67108864   (4 x 8192*512 f32)
  float* rowsum = (float*)(ws + 218103808);      // 32768
  float* colsum = (float*)(ws + 218136576);      // 32768
  float* t1     = (float*)(ws + 218169344);      // 32768 -> end 218202112

  k0_init<<<32, 256, 0, stream>>>(rowsum, colsum, out);
  k1a_convert_rowsum<<<512, 256, 0, stream>>>(adj, Abf, rowsum);
  k1b_colsum<<<1024, 256, 0, stream>>>(Abf, colsum);
  k2_scale<<<NN, 128, 0, stream>>>(X, rowsum, colsum, Y, t1);
  k2b_transpose<<<dim3(128, 8), 256, 0, stream>>>(Y, Yt);
  k3_gemm<<<256, 512, 0, stream>>>(Abf, Yt, Z);
  k4_reduce<<<512, 256, 0, stream>>>(Z, Y, t1, out);
}